// Round 7
// baseline (169.391 us; speedup 1.0000x reference)
//
#include <hip/hip_runtime.h>

// UniformBottomUpHTMM: T=64 trees, depth 10 (N1=2047 heap), C=16, M=64,
// G=16. r18: occupancy via register dieting. r17 (tables + b128 LDS) hit
// 82us with ZERO memory traffic but VGPR=212 -> 2 waves/SIMD; VALU-busy
// time is only ~16us of the 82 -> latency-stall-bound from thin TLP.
// Cross-round evidence occupancy dominates: r13 (16 waves/CU, 140MB spill)
// 84us ~= r17 (8 waves/CU, clean) 82us.
// Changes vs r17:
//  1. matvec slimmed: no tarr[16]; rows consumed in groups of 4 straight
//     into bp[q] (peak live ~36 floats inside).
//  2. '#pragma unroll 1' on the c9 subtree loop: one subtree's working
//     set live at a time; also halves leaf-phase code size (I$).
//  3. __launch_bounds__(256,2): 128-VGPR cap. Demand est ~90-110 -> fits.
//     LDS 37.5KB x4 = 150KB < 160KB -> 4 blocks/CU, 16 waves/CU.
// Tripwire: WRITE_SIZE ~4KB now; if it jumps, cap<demand again (falsified).
// Structure: 1024 independent blocks, one (t,g) each, no workspace/atomics.

#define C_DIM 16
#define M_DIM 64
#define G_DIM 16
#define T_TREES 64
#define N1 2047
#define NBLOCKS (T_TREES * G_DIM)   // 1024
#define BTS 20                      // padded row stride (floats) for xv-tables

__device__ __forceinline__ float4 f4add(float4 a, float4 b) {
    return make_float4(a.x + b.x, a.y + b.y, a.z + b.z, a.w + b.w);
}
__device__ __forceinline__ float4 f4mul(float4 a, float4 b) {
    return make_float4(a.x * b.x, a.y * b.y, a.z * b.z, a.w * b.w);
}
__device__ __forceinline__ float4 f4fma(float4 a, float4 b, float4 c) {
    return make_float4(fmaf(a.x, b.x, c.x), fmaf(a.y, b.y, c.y),
                       fmaf(a.z, b.z, c.z), fmaf(a.w, b.w, c.w));
}
__device__ __forceinline__ float hsum4(float4 a) { return a.x + a.y + a.z + a.w; }

// bp[q] = (A[4q+r]·s) * Bt[4q+r]; returns nu = sum(bp). Slim: row-group
// temps consumed immediately, no 16-wide tarr.
__device__ __forceinline__ float matvec_bt(const float* __restrict__ A,
                                           const float* __restrict__ bt,
                                           const float4 sv[4], float4 bp[4])
{
    float nu = 0.f;
    #pragma unroll
    for (int q = 0; q < 4; ++q) {
        const float4 b4 = *(const float4*)(bt + 4 * q);
        float tr0, tr1, tr2, tr3;
        {
            const float4* ar = (const float4*)(A + (4 * q + 0) * 16);
            float4 m = f4mul(ar[0], sv[0]);
            m = f4fma(ar[1], sv[1], m); m = f4fma(ar[2], sv[2], m);
            m = f4fma(ar[3], sv[3], m); tr0 = hsum4(m);
        }
        {
            const float4* ar = (const float4*)(A + (4 * q + 1) * 16);
            float4 m = f4mul(ar[0], sv[0]);
            m = f4fma(ar[1], sv[1], m); m = f4fma(ar[2], sv[2], m);
            m = f4fma(ar[3], sv[3], m); tr1 = hsum4(m);
        }
        {
            const float4* ar = (const float4*)(A + (4 * q + 2) * 16);
            float4 m = f4mul(ar[0], sv[0]);
            m = f4fma(ar[1], sv[1], m); m = f4fma(ar[2], sv[2], m);
            m = f4fma(ar[3], sv[3], m); tr2 = hsum4(m);
        }
        {
            const float4* ar = (const float4*)(A + (4 * q + 3) * 16);
            float4 m = f4mul(ar[0], sv[0]);
            m = f4fma(ar[1], sv[1], m); m = f4fma(ar[2], sv[2], m);
            m = f4fma(ar[3], sv[3], m); tr3 = hsum4(m);
        }
        bp[q] = f4mul(make_float4(tr0, tr1, tr2, tr3), b4);
        nu += hsum4(bp[q]);
    }
    return nu;
}

__global__ __launch_bounds__(256, 2) void htmm_fused(
    const int* __restrict__ x,
    const int* __restrict__ inv_map,
    const float* __restrict__ lA,
    const float* __restrict__ lB,
    const float* __restrict__ lPi,
    float* __restrict__ out)
{
    const int bid = blockIdx.x;           // 1024 blocks: g = bid>>6, t = bid&63
    const int tid = threadIdx.x;
    const int g = bid >> 6;
    const int t = bid & (T_TREES - 1);

    __shared__ __align__(16) float sA[C_DIM * C_DIM];
    __shared__ __align__(16) float sBt[M_DIM * BTS];   // Bt[xv][c], stride 20
    __shared__ __align__(16) float sPB[M_DIM * BTS];   // 0.5*Pi*B/nu per xv
    __shared__ float sLog[M_DIM];                      // log(nu_leaf(xv))
    __shared__ float sPi[C_DIM];
    __shared__ __align__(16) unsigned char xs[2048];
    __shared__ float buf0[C_DIM * 256];   // L8 betas (SoA stride 256)
    __shared__ float buf1[C_DIM * 128];
    __shared__ float wsum[4];

    // ---- tree symbols (coalesced; 16 same-tree blocks share L2) ----
    {
        const int base = t * N1;
        for (int i = tid; i < N1; i += 256)
            xs[i] = (unsigned char)x[inv_map[base + i]];
    }
    // ---- A softmax (over i within 16-lane segments) ----
    {
        int j = tid >> 4, i = tid & 15;
        float v = lA[(i * C_DIM + j) * G_DIM + g];
        float mx = v;
        #pragma unroll
        for (int m = 1; m < 16; m <<= 1) mx = fmaxf(mx, __shfl_xor(mx, m, 16));
        float e = __expf(v - mx);
        float s = e;
        #pragma unroll
        for (int m = 1; m < 16; m <<= 1) s += __shfl_xor(s, m, 16);
        sA[i * C_DIM + j] = e / s;
    }
    // ---- B softmax (over m), written TRANSPOSED: sBt[xv*BTS + c] ----
    {
        int c = tid >> 4, l16 = tid & 15;
        float e0 = lB[(c * M_DIM + l16 +  0) * G_DIM + g];
        float e1 = lB[(c * M_DIM + l16 + 16) * G_DIM + g];
        float e2 = lB[(c * M_DIM + l16 + 32) * G_DIM + g];
        float e3 = lB[(c * M_DIM + l16 + 48) * G_DIM + g];
        float mx = fmaxf(fmaxf(e0, e1), fmaxf(e2, e3));
        #pragma unroll
        for (int m = 1; m < 16; m <<= 1) mx = fmaxf(mx, __shfl_xor(mx, m, 16));
        e0 = __expf(e0 - mx); e1 = __expf(e1 - mx);
        e2 = __expf(e2 - mx); e3 = __expf(e3 - mx);
        float s = e0 + e1 + e2 + e3;
        #pragma unroll
        for (int m = 1; m < 16; m <<= 1) s += __shfl_xor(s, m, 16);
        float inv = 1.f / s;
        sBt[(l16 +  0) * BTS + c] = e0 * inv;
        sBt[(l16 + 16) * BTS + c] = e1 * inv;
        sBt[(l16 + 32) * BTS + c] = e2 * inv;
        sBt[(l16 + 48) * BTS + c] = e3 * inv;
    }
    if (tid < C_DIM) {  // Pi softmax
        float v = lPi[tid * G_DIM + g];
        float mx = v;
        #pragma unroll
        for (int m = 1; m < 16; m <<= 1) mx = fmaxf(mx, __shfl_xor(mx, m, 16));
        float e = __expf(v - mx);
        float s = e;
        #pragma unroll
        for (int m = 1; m < 16; m <<= 1) s += __shfl_xor(s, m, 16);
        sPi[tid] = e / s;
    }
    __syncthreads();

    // ---- leaf tables: PB[xv][k] = 0.5*Pi[k]*Bt[xv][k]/nu, logNu[xv] ----
    if (tid < M_DIM) {
        const int xv = tid;
        float pb[16]; float nu = 0.f;
        #pragma unroll
        for (int k = 0; k < 16; ++k) {
            pb[k] = sPi[k] * sBt[xv * BTS + k];
            nu += pb[k];
        }
        const float inv = 0.5f / nu;
        #pragma unroll
        for (int k = 0; k < 16; ++k) sPB[xv * BTS + k] = pb[k] * inv;
        sLog[xv] = __logf(nu);
    }
    __syncthreads();

    float ll = 0.f;

    // ---- fused leaves (table) + L9 + L8: one L8 node per thread ----
    // c9 loop ROLLED: one subtree's working set live at a time.
    {
        const int idx = tid;
        const int p8  = 255 + idx;
        float4 s8v[4];
        #pragma unroll
        for (int q = 0; q < 4; ++q) s8v[q] = make_float4(0.f, 0.f, 0.f, 0.f);

        #pragma unroll 1
        for (int c9 = 0; c9 < 2; ++c9) {
            const int p9 = 2 * p8 + 1 + c9;
            const int xl = xs[2 * p9 + 1], xr = xs[2 * p9 + 2];
            const float* pl = &sPB[xl * BTS];
            const float* pr = &sPB[xr * BTS];
            float4 s9v[4];
            #pragma unroll
            for (int q = 0; q < 4; ++q)
                s9v[q] = f4add(*(const float4*)(pl + 4*q), *(const float4*)(pr + 4*q));
            ll += sLog[xl] + sLog[xr];

            const int xv = xs[p9];
            float4 bp[4];
            float nu = matvec_bt(sA, &sBt[xv * BTS], s9v, bp);
            ll += __logf(nu);
            const float inv = 0.5f / nu;
            const float4 iv = make_float4(inv, inv, inv, inv);
            #pragma unroll
            for (int q = 0; q < 4; ++q) s8v[q] = f4fma(bp[q], iv, s8v[q]);
        }
        const int xv = xs[p8];
        float4 bp[4];
        float nu = matvec_bt(sA, &sBt[xv * BTS], s8v, bp);
        ll += __logf(nu);
        const float inv = 1.f / nu;
        #pragma unroll
        for (int q = 0; q < 4; ++q) {
            buf0[(4*q + 0) * 256 + idx] = bp[q].x * inv;
            buf0[(4*q + 1) * 256 + idx] = bp[q].y * inv;
            buf0[(4*q + 2) * 256 + idx] = bp[q].z * inv;
            buf0[(4*q + 3) * 256 + idx] = bp[q].w * inv;
        }
    }
    __syncthreads();

    // ---- L7: 128 nodes ----
    if (tid < 128) {
        const int idx = tid;
        float4 sv[4];
        #pragma unroll
        for (int q = 0; q < 4; ++q) {
            float2 c0 = *(const float2*)(&buf0[(4*q + 0) * 256 + 2 * idx]);
            float2 c1 = *(const float2*)(&buf0[(4*q + 1) * 256 + 2 * idx]);
            float2 c2 = *(const float2*)(&buf0[(4*q + 2) * 256 + 2 * idx]);
            float2 c3 = *(const float2*)(&buf0[(4*q + 3) * 256 + 2 * idx]);
            sv[q] = make_float4(0.5f * (c0.x + c0.y), 0.5f * (c1.x + c1.y),
                                0.5f * (c2.x + c2.y), 0.5f * (c3.x + c3.y));
        }
        const int xv = xs[127 + idx];
        float4 bp[4];
        float nu = matvec_bt(sA, &sBt[xv * BTS], sv, bp);
        ll += __logf(nu);
        const float inv = 1.f / nu;
        #pragma unroll
        for (int q = 0; q < 4; ++q) {
            buf1[(4*q + 0) * 128 + idx] = bp[q].x * inv;
            buf1[(4*q + 1) * 128 + idx] = bp[q].y * inv;
            buf1[(4*q + 2) * 128 + idx] = bp[q].z * inv;
            buf1[(4*q + 3) * 128 + idx] = bp[q].w * inv;
        }
    }
    __syncthreads();

    // ---- L6..L0 (64..1 nodes): wave 0 only, LDS fences not barriers ----
    if (tid < 64) {
        float* cur = buf1; int cs = 128;
        float* nxt = buf0; int ns = 256;
        for (int cnt2 = 64; cnt2 >= 1; cnt2 >>= 1) {
            if (tid < cnt2) {
                const int idx = tid;
                float4 sv[4];
                #pragma unroll
                for (int q = 0; q < 4; ++q) {
                    float2 c0 = *(const float2*)(&cur[(4*q + 0) * cs + 2 * idx]);
                    float2 c1 = *(const float2*)(&cur[(4*q + 1) * cs + 2 * idx]);
                    float2 c2 = *(const float2*)(&cur[(4*q + 2) * cs + 2 * idx]);
                    float2 c3 = *(const float2*)(&cur[(4*q + 3) * cs + 2 * idx]);
                    sv[q] = make_float4(0.5f * (c0.x + c0.y), 0.5f * (c1.x + c1.y),
                                        0.5f * (c2.x + c2.y), 0.5f * (c3.x + c3.y));
                }
                const int xv = xs[cnt2 - 1 + idx];
                float4 bp[4];
                float nu = matvec_bt(sA, &sBt[xv * BTS], sv, bp);
                ll += __logf(nu);
                const float inv = 1.f / nu;
                #pragma unroll
                for (int q = 0; q < 4; ++q) {
                    nxt[(4*q + 0) * ns + idx] = bp[q].x * inv;
                    nxt[(4*q + 1) * ns + idx] = bp[q].y * inv;
                    nxt[(4*q + 2) * ns + idx] = bp[q].z * inv;
                    nxt[(4*q + 3) * ns + idx] = bp[q].w * inv;
                }
            }
            asm volatile("s_waitcnt lgkmcnt(0)" ::: "memory");
            __builtin_amdgcn_wave_barrier();
            float* tp = cur; cur = nxt; nxt = tp;
            int ts = cs; cs = ns; ns = ts;
        }
    }

    // ---- reduce ll across block ----
    float v = ll;
    #pragma unroll
    for (int off = 32; off > 0; off >>= 1) v += __shfl_down(v, off, 64);
    if ((tid & 63) == 0) wsum[tid >> 6] = v;
    __syncthreads();
    if (tid == 0) out[t * G_DIM + g] = wsum[0] + wsum[1] + wsum[2] + wsum[3];
}

extern "C" void kernel_launch(void* const* d_in, const int* in_sizes, int n_in,
                              void* d_out, int out_size, void* d_ws, size_t ws_size,
                              hipStream_t stream) {
    const int*   x       = (const int*)d_in[0];
    const int*   inv_map = (const int*)d_in[6];
    const float* lA      = (const float*)d_in[7];
    const float* lB      = (const float*)d_in[8];
    const float* lPi     = (const float*)d_in[9];
    float* out = (float*)d_out;

    htmm_fused<<<dim3(NBLOCKS), dim3(256), 0, stream>>>(
        x, inv_map, lA, lB, lPi, out);
}

// Round 8
// 120.747 us; speedup vs baseline: 1.4029x; 1.4029x over previous
//
#include <hip/hip_runtime.h>

// UniformBottomUpHTMM: T=64 trees, depth 10 (N1=2047 heap), C=16, M=64,
// G=16. r19: register-demand reduction via HARD scheduling fences.
// Ledger: natural demand ~210-240 VGPR regardless of source shaping
// (r13 full-unroll 360B/thr spill @cap128; r15 rolled ~320B; r18 rolled+
// slim 450B) -- pragmas don't stop hipcc's pre-RA scheduler from hoisting
// and pipelining across phase boundaries. r17 (cap 256) is spill-free at
// VGPR=212 -> 2 waves/SIMD, 82us, VALUBusy 20% = latency-bound.
// Demand source: inside each matvec the compiler issues all 16
// ds_read_b128 A-row loads upfront = 64 VGPRs in flight, + sv/bp/s8v.
// Fix: __builtin_amdgcn_sched_barrier(0) -- a fence the scheduler CANNOT
// cross: (1) matvec split into two 8-row halves, fence between => <=8
// b128 in flight (32 regs); (2) fence after each c9 subtree so the two
// subtrees' working sets are never co-live. Cap stays 256 ((256,1)):
// spill impossible by construction; occupancy follows actual VGPR.
// Worst case neutral (~82us); VGPR<=168 -> 3 waves/SIMD, <=128 -> 4.
// Structure: 1024 independent blocks, one (t,g) each, no workspace/atomics.

#define C_DIM 16
#define M_DIM 64
#define G_DIM 16
#define T_TREES 64
#define N1 2047
#define NBLOCKS (T_TREES * G_DIM)   // 1024
#define BTS 20                      // padded row stride (floats) for xv-tables

__device__ __forceinline__ float4 f4add(float4 a, float4 b) {
    return make_float4(a.x + b.x, a.y + b.y, a.z + b.z, a.w + b.w);
}
__device__ __forceinline__ float4 f4mul(float4 a, float4 b) {
    return make_float4(a.x * b.x, a.y * b.y, a.z * b.z, a.w * b.w);
}
__device__ __forceinline__ float4 f4fma(float4 a, float4 b, float4 c) {
    return make_float4(fmaf(a.x, b.x, c.x), fmaf(a.y, b.y, c.y),
                       fmaf(a.z, b.z, c.z), fmaf(a.w, b.w, c.w));
}
__device__ __forceinline__ float hsum4(float4 a) { return a.x + a.y + a.z + a.w; }

// bp[q] = (A[4q+r]·s) * Bt[4q+r]; returns nu = sum(bp).
// Two 8-row halves with a hard sched fence between: caps in-flight
// ds_read_b128 at 8 (32 VGPRs) instead of 16 (64 VGPRs).
__device__ __forceinline__ float matvec_bt(const float* __restrict__ A,
                                           const float* __restrict__ bt,
                                           const float4 sv[4], float4 bp[4])
{
    float nu = 0.f;
    #pragma unroll
    for (int h = 0; h < 2; ++h) {
        #pragma unroll
        for (int q = 2 * h; q < 2 * h + 2; ++q) {
            const float4 b4 = *(const float4*)(bt + 4 * q);
            float tr[4];
            #pragma unroll
            for (int r = 0; r < 4; ++r) {
                const float4* ar = (const float4*)(A + (4 * q + r) * 16);
                float4 m = f4mul(ar[0], sv[0]);
                m = f4fma(ar[1], sv[1], m);
                m = f4fma(ar[2], sv[2], m);
                m = f4fma(ar[3], sv[3], m);
                tr[r] = hsum4(m);
            }
            bp[q] = f4mul(make_float4(tr[0], tr[1], tr[2], tr[3]), b4);
            nu += hsum4(bp[q]);
        }
        __builtin_amdgcn_sched_barrier(0);   // liveness fence: half-matvec
    }
    return nu;
}

__global__ __launch_bounds__(256, 1) void htmm_fused(
    const int* __restrict__ x,
    const int* __restrict__ inv_map,
    const float* __restrict__ lA,
    const float* __restrict__ lB,
    const float* __restrict__ lPi,
    float* __restrict__ out)
{
    const int bid = blockIdx.x;           // 1024 blocks: g = bid>>6, t = bid&63
    const int tid = threadIdx.x;
    const int g = bid >> 6;
    const int t = bid & (T_TREES - 1);

    __shared__ __align__(16) float sA[C_DIM * C_DIM];
    __shared__ __align__(16) float sBt[M_DIM * BTS];   // Bt[xv][c], stride 20
    __shared__ __align__(16) float sPB[M_DIM * BTS];   // 0.5*Pi*B/nu per xv
    __shared__ float sLog[M_DIM];                      // log(nu_leaf(xv))
    __shared__ float sPi[C_DIM];
    __shared__ __align__(16) unsigned char xs[2048];
    __shared__ float buf0[C_DIM * 256];   // L8 betas (SoA stride 256)
    __shared__ float buf1[C_DIM * 128];
    __shared__ float wsum[4];

    // ---- tree symbols (coalesced; 16 same-tree blocks share L2) ----
    {
        const int base = t * N1;
        for (int i = tid; i < N1; i += 256)
            xs[i] = (unsigned char)x[inv_map[base + i]];
    }
    // ---- A softmax (over i within 16-lane segments) ----
    {
        int j = tid >> 4, i = tid & 15;
        float v = lA[(i * C_DIM + j) * G_DIM + g];
        float mx = v;
        #pragma unroll
        for (int m = 1; m < 16; m <<= 1) mx = fmaxf(mx, __shfl_xor(mx, m, 16));
        float e = __expf(v - mx);
        float s = e;
        #pragma unroll
        for (int m = 1; m < 16; m <<= 1) s += __shfl_xor(s, m, 16);
        sA[i * C_DIM + j] = e / s;
    }
    // ---- B softmax (over m), written TRANSPOSED: sBt[xv*BTS + c] ----
    {
        int c = tid >> 4, l16 = tid & 15;
        float e0 = lB[(c * M_DIM + l16 +  0) * G_DIM + g];
        float e1 = lB[(c * M_DIM + l16 + 16) * G_DIM + g];
        float e2 = lB[(c * M_DIM + l16 + 32) * G_DIM + g];
        float e3 = lB[(c * M_DIM + l16 + 48) * G_DIM + g];
        float mx = fmaxf(fmaxf(e0, e1), fmaxf(e2, e3));
        #pragma unroll
        for (int m = 1; m < 16; m <<= 1) mx = fmaxf(mx, __shfl_xor(mx, m, 16));
        e0 = __expf(e0 - mx); e1 = __expf(e1 - mx);
        e2 = __expf(e2 - mx); e3 = __expf(e3 - mx);
        float s = e0 + e1 + e2 + e3;
        #pragma unroll
        for (int m = 1; m < 16; m <<= 1) s += __shfl_xor(s, m, 16);
        float inv = 1.f / s;
        sBt[(l16 +  0) * BTS + c] = e0 * inv;
        sBt[(l16 + 16) * BTS + c] = e1 * inv;
        sBt[(l16 + 32) * BTS + c] = e2 * inv;
        sBt[(l16 + 48) * BTS + c] = e3 * inv;
    }
    if (tid < C_DIM) {  // Pi softmax
        float v = lPi[tid * G_DIM + g];
        float mx = v;
        #pragma unroll
        for (int m = 1; m < 16; m <<= 1) mx = fmaxf(mx, __shfl_xor(mx, m, 16));
        float e = __expf(v - mx);
        float s = e;
        #pragma unroll
        for (int m = 1; m < 16; m <<= 1) s += __shfl_xor(s, m, 16);
        sPi[tid] = e / s;
    }
    __syncthreads();

    // ---- leaf tables: PB[xv][k] = 0.5*Pi[k]*Bt[xv][k]/nu, logNu[xv] ----
    if (tid < M_DIM) {
        const int xv = tid;
        float pb[16]; float nu = 0.f;
        #pragma unroll
        for (int k = 0; k < 16; ++k) {
            pb[k] = sPi[k] * sBt[xv * BTS + k];
            nu += pb[k];
        }
        const float inv = 0.5f / nu;
        #pragma unroll
        for (int k = 0; k < 16; ++k) sPB[xv * BTS + k] = pb[k] * inv;
        sLog[xv] = __logf(nu);
    }
    __syncthreads();

    float ll = 0.f;

    // ---- fused leaves (table) + L9 + L8: one L8 node per thread ----
    {
        const int idx = tid;
        const int p8  = 255 + idx;
        float4 s8v[4];
        #pragma unroll
        for (int q = 0; q < 4; ++q) s8v[q] = make_float4(0.f, 0.f, 0.f, 0.f);

        #pragma unroll
        for (int c9 = 0; c9 < 2; ++c9) {
            const int p9 = 2 * p8 + 1 + c9;
            const int xl = xs[2 * p9 + 1], xr = xs[2 * p9 + 2];
            const float* pl = &sPB[xl * BTS];
            const float* pr = &sPB[xr * BTS];
            float4 s9v[4];
            #pragma unroll
            for (int q = 0; q < 4; ++q)
                s9v[q] = f4add(*(const float4*)(pl + 4*q), *(const float4*)(pr + 4*q));
            ll += sLog[xl] + sLog[xr];

            const int xv = xs[p9];
            float4 bp[4];
            float nu = matvec_bt(sA, &sBt[xv * BTS], s9v, bp);
            ll += __logf(nu);
            const float inv = 0.5f / nu;
            const float4 iv = make_float4(inv, inv, inv, inv);
            #pragma unroll
            for (int q = 0; q < 4; ++q) s8v[q] = f4fma(bp[q], iv, s8v[q]);
            __builtin_amdgcn_sched_barrier(0);   // liveness fence: subtree done
        }
        const int xv = xs[p8];
        float4 bp[4];
        float nu = matvec_bt(sA, &sBt[xv * BTS], s8v, bp);
        ll += __logf(nu);
        const float inv = 1.f / nu;
        #pragma unroll
        for (int q = 0; q < 4; ++q) {
            buf0[(4*q + 0) * 256 + idx] = bp[q].x * inv;
            buf0[(4*q + 1) * 256 + idx] = bp[q].y * inv;
            buf0[(4*q + 2) * 256 + idx] = bp[q].z * inv;
            buf0[(4*q + 3) * 256 + idx] = bp[q].w * inv;
        }
    }
    __syncthreads();

    // ---- L7: 128 nodes ----
    if (tid < 128) {
        const int idx = tid;
        float4 sv[4];
        #pragma unroll
        for (int q = 0; q < 4; ++q) {
            float2 c0 = *(const float2*)(&buf0[(4*q + 0) * 256 + 2 * idx]);
            float2 c1 = *(const float2*)(&buf0[(4*q + 1) * 256 + 2 * idx]);
            float2 c2 = *(const float2*)(&buf0[(4*q + 2) * 256 + 2 * idx]);
            float2 c3 = *(const float2*)(&buf0[(4*q + 3) * 256 + 2 * idx]);
            sv[q] = make_float4(0.5f * (c0.x + c0.y), 0.5f * (c1.x + c1.y),
                                0.5f * (c2.x + c2.y), 0.5f * (c3.x + c3.y));
        }
        const int xv = xs[127 + idx];
        float4 bp[4];
        float nu = matvec_bt(sA, &sBt[xv * BTS], sv, bp);
        ll += __logf(nu);
        const float inv = 1.f / nu;
        #pragma unroll
        for (int q = 0; q < 4; ++q) {
            buf1[(4*q + 0) * 128 + idx] = bp[q].x * inv;
            buf1[(4*q + 1) * 128 + idx] = bp[q].y * inv;
            buf1[(4*q + 2) * 128 + idx] = bp[q].z * inv;
            buf1[(4*q + 3) * 128 + idx] = bp[q].w * inv;
        }
    }
    __syncthreads();

    // ---- L6..L0 (64..1 nodes): wave 0 only, LDS fences not barriers ----
    if (tid < 64) {
        float* cur = buf1; int cs = 128;
        float* nxt = buf0; int ns = 256;
        for (int cnt2 = 64; cnt2 >= 1; cnt2 >>= 1) {
            if (tid < cnt2) {
                const int idx = tid;
                float4 sv[4];
                #pragma unroll
                for (int q = 0; q < 4; ++q) {
                    float2 c0 = *(const float2*)(&cur[(4*q + 0) * cs + 2 * idx]);
                    float2 c1 = *(const float2*)(&cur[(4*q + 1) * cs + 2 * idx]);
                    float2 c2 = *(const float2*)(&cur[(4*q + 2) * cs + 2 * idx]);
                    float2 c3 = *(const float2*)(&cur[(4*q + 3) * cs + 2 * idx]);
                    sv[q] = make_float4(0.5f * (c0.x + c0.y), 0.5f * (c1.x + c1.y),
                                        0.5f * (c2.x + c2.y), 0.5f * (c3.x + c3.y));
                }
                const int xv = xs[cnt2 - 1 + idx];
                float4 bp[4];
                float nu = matvec_bt(sA, &sBt[xv * BTS], sv, bp);
                ll += __logf(nu);
                const float inv = 1.f / nu;
                #pragma unroll
                for (int q = 0; q < 4; ++q) {
                    nxt[(4*q + 0) * ns + idx] = bp[q].x * inv;
                    nxt[(4*q + 1) * ns + idx] = bp[q].y * inv;
                    nxt[(4*q + 2) * ns + idx] = bp[q].z * inv;
                    nxt[(4*q + 3) * ns + idx] = bp[q].w * inv;
                }
            }
            asm volatile("s_waitcnt lgkmcnt(0)" ::: "memory");
            __builtin_amdgcn_wave_barrier();
            float* tp = cur; cur = nxt; nxt = tp;
            int ts = cs; cs = ns; ns = ts;
        }
    }

    // ---- reduce ll across block ----
    float v = ll;
    #pragma unroll
    for (int off = 32; off > 0; off >>= 1) v += __shfl_down(v, off, 64);
    if ((tid & 63) == 0) wsum[tid >> 6] = v;
    __syncthreads();
    if (tid == 0) out[t * G_DIM + g] = wsum[0] + wsum[1] + wsum[2] + wsum[3];
}

extern "C" void kernel_launch(void* const* d_in, const int* in_sizes, int n_in,
                              void* d_out, int out_size, void* d_ws, size_t ws_size,
                              hipStream_t stream) {
    const int*   x       = (const int*)d_in[0];
    const int*   inv_map = (const int*)d_in[6];
    const float* lA      = (const float*)d_in[7];
    const float* lB      = (const float*)d_in[8];
    const float* lPi     = (const float*)d_in[9];
    float* out = (float*)d_out;

    htmm_fused<<<dim3(NBLOCKS), dim3(256), 0, stream>>>(
        x, inv_map, lA, lB, lPi, out);
}